// Round 4
// baseline (181.207 us; speedup 1.0000x reference)
//
#include <hip/hip_runtime.h>

#define DIM   128
#define HALF  64          // columns per slice (2 slices, XCD-parity L2 residency)
#define CPT   256         // chars per wave-chunk
#define TAIL  64          // staged lookahead for cross-chunk tails
#define WPB   4           // waves per block

// out = N - <H,T>_F / (||H||_F ||T||_F).  T never materialized; hh folded at
// boundary events (each non-empty segment starts in exactly one chunk); empty
// segments via ballot'd gap loop + reduce-kernel ends.
// PAIR layout: within the 64-col slice a char row is 256 B = 32 lanes x float2.
// Lanes 0-31 carry char 2p, lanes 32-63 char 2p+1 -> ONE wave load fetches two
// chars (512 B) -> half the VMEM instructions of the per-char layout, same
// slice L2 residency. acc is float2 of column-pair partials split across lane
// halves; ht is linear (no combine needed); tt combines halves via
// __shfl_xor(..,32) at flush; fast-path tt/hh are lane-duplicated -> 0.5x at
// the end. Boundary head rows: simple chained prefetch at the boundary
// (proven round-0 form), used one segment later.
__global__ __launch_bounds__(256) void fused_kernel(
    const float* __restrict__ char_emb,
    const float* __restrict__ ent,
    const int* __restrict__ head_ids,
    const int* __restrict__ char_ids,
    const int* __restrict__ seg_ids,
    float* __restrict__ pb,        // [gridDim.x*3] block partials: ht,tt,hh
    int total_chars, int n_triples)
{
    __shared__ __align__(16) int s_off[WPB][CPT + TAIL];  // (cid<<9)+sco
    __shared__ int s_sid[WPB][CPT + TAIL];
    __shared__ float r_scr[3][WPB];

    const int tid  = threadIdx.x;
    const int lane = tid & 63;
    const int wid  = tid >> 6;
    const int half = lane >> 5;               // 0: even char of pair, 1: odd
    const int sub  = lane & 31;               // column-pair index within slice
    const int colb2 = sub << 3;               // byte offset of lane's float2
    const float mlo = (half == 0) ? 1.f : 0.f;
    const float mhi = 1.f - mlo;

    float ht = 0.f, tt = 0.f, hh = 0.f;
    float tt2 = 0.f, hh2 = 0.f;               // lane-duplicated (0.5x at end)

    const int slice = blockIdx.x & 1;         // XCD-parity slice mapping
    const int sco   = slice << 8;             // slice*64 cols*4B
    const int chunk = (blockIdx.x >> 1) * WPB + wid;
    const int start = chunk * CPT;
    const int len   = min(CPT, total_chars - start);
    const int sl    = min(CPT + TAIL, total_chars - start);
    const char* cb  = (const char*)char_emb;
    const char* eb  = (const char*)ent + sco + colb2;   // pair-layout head base
    const float* ee = ent + slice * HALF + lane;        // col-layout (gaps/fallback)

    // ---- stage offsets + sids (wave-private region; no barrier needed) ----
    for (int c = lane; c < sl; c += 64) {
        s_off[wid][c] = (char_ids[start + c] << 9) + sco;
        s_sid[wid][c] = seg_ids[start + c];
    }

    // ---- boundary masks (SGPR) + gap-hh (off critical path) ----
    unsigned long long mk[4] = {0ull, 0ull, 0ull, 0ull};
    if (len == CPT) {
#pragma unroll
        for (int grp = 0; grp < 4; ++grp) {
            const int c = start + grp * 64 + lane;
            const int s1 = seg_ids[c];
            const int s0 = (c > 0) ? seg_ids[c - 1] : (s1 + 1); // char 0: boundary
            mk[grp] = __ballot(s1 != s0);
            // empty triples between s0 and s1: statistically never taken
            unsigned long long gapm = __ballot(s1 > s0 + 1);
            while (gapm) {
                const int l  = __ffsll((long long)gapm) - 1;
                const int g0 = __shfl(s0, l);
                const int g1 = __shfl(s1, l);
                for (int g = g0 + 1; g < g1; ++g) {
                    const float gv = ee[(size_t)head_ids[g] * DIM];
                    hh = fmaf(gv, gv, hh);
                }
                gapm &= gapm - 1;
            }
        }
    }

    if (len == CPT) {
        // -------- fast path (pair loads) --------
        float2 hv;  hv.x = 0.f;  hv.y = 0.f;
        float2 acc; acc.x = 0.f; acc.y = 0.f;
        bool live = false;      // first flush dropped iff chunk starts mid-segment
        float2 vA[8], vB[8];

// flush current segment: ht is exact without combine; tt needs half-combine
#define FLUSH2 { \
    const float cx = acc.x + __shfl_xor(acc.x, 32); \
    const float cy = acc.y + __shfl_xor(acc.y, 32); \
    ht = fmaf(hv.x, acc.x, ht); ht = fmaf(hv.y, acc.y, ht); \
    tt2 = fmaf(cx, cx, tt2); tt2 = fmaf(cy, cy, tt2); }

// advance to segment starting at staged char index CI (chained prefetch + hh)
#define ADV2(CI) { \
    const int cs_ = __builtin_amdgcn_readfirstlane(s_sid[wid][CI]); \
    const int hid_ = head_ids[cs_]; \
    hv = *(const float2*)(eb + ((size_t)(unsigned)hid_ << 9)); \
    hh2 = fmaf(hv.x, hv.x, hh2); hh2 = fmaf(hv.y, hv.y, hh2); }

#define PF2(BUF, B) { \
    _Pragma("unroll") \
    for (int q = 0; q < 4; ++q) { \
        const int4 o4 = *(const int4*)&s_off[wid][(B) * 16 + q * 4]; \
        const int oA = half ? o4.y : o4.x; \
        const int oB = half ? o4.w : o4.z; \
        BUF[q * 2 + 0] = *(const float2*)(cb + (size_t)(unsigned)(oA + colb2)); \
        BUF[q * 2 + 1] = *(const float2*)(cb + (size_t)(unsigned)(oB + colb2)); \
    } }

#define CS2(BUF, B) { \
    const unsigned b16 = (unsigned)((mk[(B) >> 2] >> (((B) & 3) * 16)) & 0xFFFFull); \
    if (b16 == 0u) { \
        _Pragma("unroll") \
        for (int j = 0; j < 8; ++j) { acc.x += BUF[j].x; acc.y += BUF[j].y; } \
    } else { \
        _Pragma("unroll") \
        for (int j = 0; j < 8; ++j) { \
            const float2 v = BUF[j]; \
            const int bb = (int)((b16 >> (2 * j)) & 3u); \
            if (bb == 0) { \
                acc.x += v.x; acc.y += v.y; \
            } else if (bb == 1) {           /* boundary at even char */ \
                if (live) { FLUSH2 } \
                ADV2((B) * 16 + 2 * j) \
                live = true; \
                acc = v; \
            } else if (bb == 2) {           /* boundary at odd char */ \
                acc.x = fmaf(v.x, mlo, acc.x); acc.y = fmaf(v.y, mlo, acc.y); \
                if (live) { FLUSH2 } \
                ADV2((B) * 16 + 2 * j + 1) \
                live = true; \
                acc.x = v.x * mhi; acc.y = v.y * mhi; \
            } else {                        /* boundaries at both: 1-char seg */ \
                if (live) { FLUSH2 } \
                ADV2((B) * 16 + 2 * j) \
                acc.x = v.x * mlo; acc.y = v.y * mlo; \
                FLUSH2 \
                ADV2((B) * 16 + 2 * j + 1) \
                live = true; \
                acc.x = v.x * mhi; acc.y = v.y * mhi; \
            } \
        } \
    } }

        PF2(vA, 0)
#pragma unroll
        for (int B = 0; B < 16; ++B) {
            if (B + 1 < 16) { if (B & 1) { PF2(vA, B + 1) } else { PF2(vB, B + 1) } }
            if (B & 1) { CS2(vB, B) } else { CS2(vA, B) }
        }

        if (live) {
            // tail: last owned segment may continue past chunk end
            int cur = __builtin_amdgcn_readfirstlane(s_sid[wid][CPT - 1]);
            int e = CPT;
            bool ended = false;
            while (e < sl) {
                const int idx = e + lane;
                const bool differ = (idx < sl) && (s_sid[wid][idx] != cur);
                const unsigned long long bm = __ballot(differ);
                const int run = bm ? (__ffsll((long long)bm) - 1)
                                   : min(64, sl - e);
                int j = 0;
                for (; j + 2 <= run; j += 2) {           // pair loads
                    const int oo = s_off[wid][e + j + half];
                    const float2 v = *(const float2*)(cb +
                        (size_t)(unsigned)(oo + colb2));
                    acc.x += v.x; acc.y += v.y;
                }
                if (j < run) {                           // lone char: lo half only
                    const int oo = s_off[wid][e + j];
                    const float2 v = *(const float2*)(cb +
                        (size_t)(unsigned)(oo + colb2));
                    acc.x = fmaf(v.x, mlo, acc.x); acc.y = fmaf(v.y, mlo, acc.y);
                }
                e += run;
                if (bm) { ended = true; break; }
            }
            if (!ended && start + sl < total_chars) {
                int gg = start + sl;                     // very rare long run
                while (gg < total_chars && seg_ids[gg] == cur) {
                    const float2 v = *(const float2*)(cb +
                        (size_t)(unsigned)((char_ids[gg] << 9) + sco + colb2));
                    acc.x = fmaf(v.x, mlo, acc.x); acc.y = fmaf(v.y, mlo, acc.y);
                    ++gg;
                }
            }
            // final flush
            FLUSH2
        }
    } else if (len > 0) {
        // -------- rare fallback (partial last chunk): scalar per char --------
        const float* cembF = char_emb + slice * HALF + lane;
        int p = 0;
        if (start > 0) {
            const int prev = seg_ids[start - 1];
            while (p < len && seg_ids[start + p] == prev) ++p;
        }
        if (p < len) {
            int cur2 = seg_ids[start + p];
            if (start > 0) {                     // gap before first owned segment
                for (int g = seg_ids[start - 1] + 1; g < cur2; ++g) {
                    const float gv = ee[(size_t)head_ids[g] * DIM];
                    hh = fmaf(gv, gv, hh);
                }
            }
            float acc1 = 0.f;
            float hv1 = ee[(size_t)head_ids[cur2] * DIM];
            hh = fmaf(hv1, hv1, hh);
            for (int c = p; c < len; ++c) {
                const int sid = seg_ids[start + c];
                if (sid != cur2) {
                    ht += hv1 * acc1; tt += acc1 * acc1;
                    for (int g = cur2 + 1; g < sid; ++g) {   // interior gaps
                        const float gv = ee[(size_t)head_ids[g] * DIM];
                        hh = fmaf(gv, gv, hh);
                    }
                    acc1 = 0.f; cur2 = sid;
                    hv1 = ee[(size_t)head_ids[cur2] * DIM];
                    hh = fmaf(hv1, hv1, hh);
                }
                acc1 += cembF[(size_t)char_ids[start + c] * DIM];
            }
            int gg = start + len;
            while (gg < total_chars && seg_ids[gg] == cur2) {
                acc1 += cembF[(size_t)char_ids[gg] * DIM];
                ++gg;
            }
            ht += hv1 * acc1; tt += acc1 * acc1;
        }
    }

    // fold lane-duplicated fast-path partials
    tt += 0.5f * tt2;
    hh += 0.5f * hh2;

    // -------- block reduce -> per-block partials (no atomics, no memset) ----
#pragma unroll
    for (int off = 32; off > 0; off >>= 1) {
        ht += __shfl_down(ht, off);
        tt += __shfl_down(tt, off);
        hh += __shfl_down(hh, off);
    }
    if (lane == 0) { r_scr[0][wid] = ht; r_scr[1][wid] = tt; r_scr[2][wid] = hh; }
    __syncthreads();
    if (tid == 0) {
        float a = 0.f, b = 0.f, c = 0.f;
#pragma unroll
        for (int w = 0; w < WPB; ++w) {
            a += r_scr[0][w]; b += r_scr[1][w]; c += r_scr[2][w];
        }
        pb[blockIdx.x * 3 + 0] = a;
        pb[blockIdx.x * 3 + 1] = b;
        pb[blockIdx.x * 3 + 2] = c;
    }
}

// final reduce: sums partials in double, adds hh for leading/trailing empty
// triples (rows with no chars before the first / after the last seg id),
// writes N - ht/sqrt(hh*tt)
__global__ __launch_bounds__(256) void reduce_kernel(
    const float* __restrict__ pb, int nb, float* __restrict__ out,
    int n_triples, const int* __restrict__ seg_ids,
    const int* __restrict__ head_ids, const float* __restrict__ ent,
    int total_chars)
{
    double ht = 0.0, tt = 0.0, hh = 0.0;
    for (int i = threadIdx.x; i < nb; i += 256) {
        ht += (double)pb[i * 3 + 0];
        tt += (double)pb[i * 3 + 1];
        hh += (double)pb[i * 3 + 2];
    }
    // leading/trailing empty triples (typically 0-3 rows)
    int first = n_triples, last = n_triples - 1;
    if (total_chars > 0) { first = seg_ids[0]; last = seg_ids[total_chars - 1]; }
    const int lead  = first;
    const int trail = n_triples - 1 - last;
    const int tot   = lead + trail;
    const float4* e4 = (const float4*)ent;
    for (int w = threadIdx.x; w < tot * 32; w += 256) {
        const int rr = w >> 5;
        const int g  = (rr < lead) ? rr : (last + 1 + (rr - lead));
        const float4 v = e4[(size_t)head_ids[g] * 32 + (w & 31)];
        hh += (double)v.x * v.x + (double)v.y * v.y
            + (double)v.z * v.z + (double)v.w * v.w;
    }
#pragma unroll
    for (int off = 32; off > 0; off >>= 1) {
        ht += __shfl_down(ht, off);
        tt += __shfl_down(tt, off);
        hh += __shfl_down(hh, off);
    }
    __shared__ double sd[3][4];
    const int wid = threadIdx.x >> 6;
    if ((threadIdx.x & 63) == 0) { sd[0][wid] = ht; sd[1][wid] = tt; sd[2][wid] = hh; }
    __syncthreads();
    if (threadIdx.x == 0) {
        double a = 0.0, b = 0.0, c = 0.0;
        for (int w = 0; w < 4; ++w) { a += sd[0][w]; b += sd[1][w]; c += sd[2][w]; }
        out[0] = (float)((double)n_triples - a / sqrt(c * b));
    }
}

extern "C" void kernel_launch(void* const* d_in, const int* in_sizes, int n_in,
                              void* d_out, int out_size, void* d_ws, size_t ws_size,
                              hipStream_t stream)
{
    const float* char_emb = (const float*)d_in[0];
    const float* ent_emb  = (const float*)d_in[1];
    const int* head_ids   = (const int*)d_in[2];
    const int* char_ids   = (const int*)d_in[3];
    const int* seg_ids    = (const int*)d_in[4];
    const int n_triples   = in_sizes[2];
    const int total_chars = in_sizes[3];

    const int n_chunks = (total_chars + CPT - 1) / CPT;
    const int bps = (n_chunks + WPB - 1) / WPB;
    const int nsb = (2 * bps > 0) ? 2 * bps : 2;   // x2 slices

    float* pb = (float*)d_ws;                      // nsb*3 floats

    fused_kernel<<<nsb, 256, 0, stream>>>(char_emb, ent_emb, head_ids,
                                          char_ids, seg_ids, pb,
                                          total_chars, n_triples);
    reduce_kernel<<<1, 256, 0, stream>>>(pb, nsb, (float*)d_out, n_triples,
                                         seg_ids, head_ids, ent_emb,
                                         total_chars);
}

// Round 5
// 178.171 us; speedup vs baseline: 1.0170x; 1.0170x over previous
//
#include <hip/hip_runtime.h>

#define DIM   128
#define HALF  64          // columns per slice (2 slices, XCD-parity L2 residency)
#define CPT   256         // chars per wave-chunk
#define TAIL  64          // staged lookahead for cross-chunk tails
#define WPB   4           // waves per block
#define QD    32          // boundary head-id queue depth (Poisson(16) tail-safe)

// out = N - <H,T>_F / (||H||_F ||T||_F).  T never materialized.
// Round-0 structure (best measured: 79us): 2-slice XCD-parity, hh strip,
// simple chained boundary flush. Two minimal deltas:
//  (1) char-gather pipeline depth 2 (3 rotating 16-deep buffers -> 32 loads
//      in flight per wave, covers ~200cy L2 latency in-wave);
//  (2) boundary head *ids* pre-gathered to a 512B LDS queue during the ballot
//      phase, consumed one segment ahead (nhid) -> boundary critical chain is
//      the row load only (id-load hop removed). No value cache, no FIFO.
__global__ __launch_bounds__(256) void fused_kernel(
    const float* __restrict__ char_emb,
    const float* __restrict__ ent,
    const int* __restrict__ head_ids,
    const int* __restrict__ char_ids,
    const int* __restrict__ seg_ids,
    float* __restrict__ pb,        // [gridDim.x*3] block partials: ht,tt,hh
    int total_chars, int n_triples, int hh_per_block)
{
    __shared__ __align__(16) int s_off[WPB][CPT + TAIL];  // (cid<<9)+sco
    __shared__ int s_sid[WPB][CPT + TAIL];
    __shared__ int s_hq[WPB][QD];                         // boundary head ids
    __shared__ float r_scr[3][WPB];

    const int tid  = threadIdx.x;
    const int lane = tid & 63;
    const int wid  = tid >> 6;
    const int colb = lane << 2;               // byte offset of lane's column

    float ht = 0.f, tt = 0.f, hh = 0.f;

    const int slice = blockIdx.x & 1;         // XCD-parity slice mapping
    const int sco   = slice << 8;             // slice*64 cols*4B
    const int chunk = (blockIdx.x >> 1) * WPB + wid;
    const int start = chunk * CPT;
    const int len   = min(CPT, total_chars - start);
    const int sl    = min(CPT + TAIL, total_chars - start);
    const char* cb  = (const char*)char_emb;
    const float* ee = ent + slice * HALF + lane;

    // ---- stage offsets + sids (wave-local region) ----
    for (int c = lane; c < sl; c += 64) {
        s_off[wid][c] = (char_ids[start + c] << 9) + sco;
        s_sid[wid][c] = seg_ids[start + c];
    }
    // ---- boundary masks (SGPR ballots) + head-id queue (rank = prefix pop) --
    unsigned long long mk[4] = {0ull, 0ull, 0ull, 0ull};
    if (len == CPT) {
        int rbase = 0;
#pragma unroll
        for (int grp = 0; grp < 4; ++grp) {
            const int c = start + grp * 64 + lane;
            const int s1 = seg_ids[c];
            const int s0 = (c > 0) ? seg_ids[c - 1] : (s1 + 1); // char 0: boundary
            const bool bnd = (s1 != s0);
            mk[grp] = __ballot(bnd);
            const int rk0 = rbase + (int)__popcll(mk[grp] & ((1ull << lane) - 1ull));
            if (bnd && rk0 < QD) s_hq[wid][rk0] = head_ids[s1];
            rbase += (int)__popcll(mk[grp]);
        }
    }
    __syncthreads();

    if (len == CPT) {
        // -------- fast path --------
        float hv = 0.f;
        float acc = 0.f;
        bool live = false;      // first flush dropped iff chunk starts mid-segment
        int rk = 0;
        int nhid = s_hq[wid][0];              // 1-ahead id (broadcast ds_read)
        float vA[16], vB[16], vC[16];

#define PF(BUF, B) { \
    _Pragma("unroll") \
    for (int q = 0; q < 4; ++q) { \
        const int4 o4 = *(const int4*)&s_off[wid][(B) * 16 + q * 4]; \
        BUF[q * 4 + 0] = *(const float*)(cb + (size_t)(unsigned)(o4.x + colb)); \
        BUF[q * 4 + 1] = *(const float*)(cb + (size_t)(unsigned)(o4.y + colb)); \
        BUF[q * 4 + 2] = *(const float*)(cb + (size_t)(unsigned)(o4.z + colb)); \
        BUF[q * 4 + 3] = *(const float*)(cb + (size_t)(unsigned)(o4.w + colb)); \
    } }

#define CS(BUF, B) { \
    _Pragma("unroll") \
    for (int j = 0; j < 16; ++j) { \
        if (mk[(B) >> 2] & (1ull << (((B) & 3) * 16 + j))) {   /* scalar bit test */ \
            if (live) { ht = fmaf(hv, acc, ht); tt = fmaf(acc, acc, tt); } \
            live = true; \
            acc = 0.f; \
            int hid_; \
            if (rk < QD) {                      /* queue hit: id already here */ \
                hid_ = nhid; \
            } else {                            /* rare overflow: chained */ \
                const int cs_ = __builtin_amdgcn_readfirstlane(s_sid[wid][(B) * 16 + j]); \
                hid_ = head_ids[cs_]; \
            } \
            ++rk; \
            nhid = s_hq[wid][rk < QD ? rk : (QD - 1)]; \
            hv = ee[(size_t)(unsigned)hid_ * DIM];   /* row load only */ \
        } \
        acc += BUF[j]; \
    } }

        PF(vA, 0)
        PF(vB, 1)
#pragma unroll
        for (int B = 0; B < 16; ++B) {
            const int nb2 = B + 2;
            if (nb2 < 16) {
                if (nb2 % 3 == 0)      { PF(vA, nb2) }
                else if (nb2 % 3 == 1) { PF(vB, nb2) }
                else                   { PF(vC, nb2) }
            }
            if (B % 3 == 0)      { CS(vA, B) }
            else if (B % 3 == 1) { CS(vB, B) }
            else                 { CS(vC, B) }
        }

        if (live) {
            // tail: last owned segment may continue past chunk end
            int cur = __builtin_amdgcn_readfirstlane(s_sid[wid][CPT - 1]);
            int e = CPT;
            bool ended = false;
            while (e < sl) {
                const int idx = e + lane;
                const bool differ = (idx < sl) && (s_sid[wid][idx] != cur);
                const unsigned long long bm = __ballot(differ);
                const int run = bm ? (__ffsll((long long)bm) - 1)
                                   : min(64, sl - e);
                for (int j = 0; j < run; j += 4) {
                    const int mm2 = min(4, run - j);
                    float vv[4];
#pragma unroll
                    for (int k = 0; k < 4; ++k) {
                        if (k < mm2)
                            vv[k] = *(const float*)(cb +
                                (size_t)(unsigned)(s_off[wid][e + j + k] + colb));
                    }
                    for (int k = 0; k < mm2; ++k) acc += vv[k];
                }
                e += run;
                if (bm) { ended = true; break; }
            }
            if (!ended && start + sl < total_chars) {
                int gg = start + sl;                 // very rare long run
                while (gg < total_chars && seg_ids[gg] == cur) {
                    acc += *(const float*)(cb +
                        (size_t)(unsigned)((char_ids[gg] << 9) + sco + colb));
                    ++gg;
                }
            }
            // final flush
            ht = fmaf(hv, acc, ht);
            tt = fmaf(acc, acc, tt);
        }
    } else if (len > 0) {
        // -------- rare fallback (partial last chunk): scalar per char --------
        const float* cembF = char_emb + slice * HALF + lane;
        int p = 0;
        if (start > 0) {
            const int prev = seg_ids[start - 1];
            while (p < len && seg_ids[start + p] == prev) ++p;
        }
        if (p < len) {
            int cur = seg_ids[start + p];
            float acc = 0.f;
            float hv = ee[(size_t)head_ids[cur] * DIM];
            for (int c = p; c < len; ++c) {
                const int sid = seg_ids[start + c];
                if (sid != cur) {
                    ht += hv * acc; tt += acc * acc;
                    acc = 0.f; cur = sid;
                    hv = ee[(size_t)head_ids[cur] * DIM];
                }
                acc += cembF[(size_t)char_ids[start + c] * DIM];
            }
            int gg = start + len;
            while (gg < total_chars && seg_ids[gg] == cur) {
                acc += cembF[(size_t)char_ids[gg] * DIM];
                ++gg;
            }
            ht += hv * acc; tt += acc * acc;
        }
    }

    // -------- hh strip for this block (covers empty segments exactly) --------
    {
        const float4* e4 = (const float4*)ent;
        const long base = (long)blockIdx.x * hh_per_block * 32;
        const long lim  = (long)n_triples * 32;
        for (int s = tid; s < hh_per_block * 32; s += 256) {
            const long f = base + s;
            if (f < lim) {
                const int row = (int)(f >> 5);
                const int hid = head_ids[row];
                const float4 v = e4[(size_t)hid * 32 + (int)(f & 31)];
                hh += v.x * v.x + v.y * v.y + v.z * v.z + v.w * v.w;
            }
        }
    }

    // -------- block reduce -> per-block partials (no atomics, no memset) ----
#pragma unroll
    for (int off = 32; off > 0; off >>= 1) {
        ht += __shfl_down(ht, off);
        tt += __shfl_down(tt, off);
        hh += __shfl_down(hh, off);
    }
    if (lane == 0) { r_scr[0][wid] = ht; r_scr[1][wid] = tt; r_scr[2][wid] = hh; }
    __syncthreads();
    if (tid == 0) {
        float a = 0.f, b = 0.f, c = 0.f;
#pragma unroll
        for (int w = 0; w < WPB; ++w) {
            a += r_scr[0][w]; b += r_scr[1][w]; c += r_scr[2][w];
        }
        pb[blockIdx.x * 3 + 0] = a;
        pb[blockIdx.x * 3 + 1] = b;
        pb[blockIdx.x * 3 + 2] = c;
    }
}

// final reduce: sums partials in double, writes N - ht/sqrt(hh*tt)
__global__ __launch_bounds__(256) void reduce_kernel(
    const float* __restrict__ pb, int nb, float* __restrict__ out,
    int n_triples)
{
    double ht = 0.0, tt = 0.0, hh = 0.0;
    for (int i = threadIdx.x; i < nb; i += 256) {
        ht += (double)pb[i * 3 + 0];
        tt += (double)pb[i * 3 + 1];
        hh += (double)pb[i * 3 + 2];
    }
#pragma unroll
    for (int off = 32; off > 0; off >>= 1) {
        ht += __shfl_down(ht, off);
        tt += __shfl_down(tt, off);
        hh += __shfl_down(hh, off);
    }
    __shared__ double sd[3][4];
    const int wid = threadIdx.x >> 6;
    if ((threadIdx.x & 63) == 0) { sd[0][wid] = ht; sd[1][wid] = tt; sd[2][wid] = hh; }
    __syncthreads();
    if (threadIdx.x == 0) {
        double a = 0.0, b = 0.0, c = 0.0;
        for (int w = 0; w < 4; ++w) { a += sd[0][w]; b += sd[1][w]; c += sd[2][w]; }
        out[0] = (float)((double)n_triples - a / sqrt(c * b));
    }
}

extern "C" void kernel_launch(void* const* d_in, const int* in_sizes, int n_in,
                              void* d_out, int out_size, void* d_ws, size_t ws_size,
                              hipStream_t stream)
{
    const float* char_emb = (const float*)d_in[0];
    const float* ent_emb  = (const float*)d_in[1];
    const int* head_ids   = (const int*)d_in[2];
    const int* char_ids   = (const int*)d_in[3];
    const int* seg_ids    = (const int*)d_in[4];
    const int n_triples   = in_sizes[2];
    const int total_chars = in_sizes[3];

    const int n_chunks = (total_chars + CPT - 1) / CPT;
    const int bps = (n_chunks + WPB - 1) / WPB;
    const int nsb = 2 * bps;                       // x2 slices
    const int hhpb = (n_triples + nsb - 1) / nsb;

    float* pb = (float*)d_ws;                      // nsb*3 floats

    fused_kernel<<<nsb, 256, 0, stream>>>(char_emb, ent_emb, head_ids,
                                          char_ids, seg_ids, pb,
                                          total_chars, n_triples, hhpb);
    reduce_kernel<<<1, 256, 0, stream>>>(pb, nsb, (float*)d_out, n_triples);
}

// Round 6
// 166.203 us; speedup vs baseline: 1.0903x; 1.0720x over previous
//
#include <hip/hip_runtime.h>

#define DIM   128
#define HALF  64          // columns per slice (2 slices, XCD-parity L2 residency)
#define CPT   256         // chars per wave-chunk
#define TAIL  64          // staged lookahead for cross-chunk tails
#define WPB   4           // waves per block

// out = N - <H,T>_F / (||H||_F ||T||_F).  T never materialized.
// Round-0 structure (best measured: 79us): 2-slice XCD-parity, depth-2 PF,
// simple chained boundary hv load. ONE delta vs round 0: the hh strip (51 MB
// of ent re-gathers, ~10% of all L2 line requests) is deleted; ||h||^2 is
// folded at each boundary-event hv load instead. The two parity slices
// partition the row's 128 columns, so the two blocks covering a chunk sum to
// the full ||h||^2 exactly once per non-empty segment. Empty segments:
// interior gaps via a ballot'd loop in the (off-critical-path) mask phase;
// leading/trailing empties in the reduce kernel.
__global__ __launch_bounds__(256) void fused_kernel(
    const float* __restrict__ char_emb,
    const float* __restrict__ ent,
    const int* __restrict__ head_ids,
    const int* __restrict__ char_ids,
    const int* __restrict__ seg_ids,
    float* __restrict__ pb,        // [gridDim.x*3] block partials: ht,tt,hh
    int total_chars)
{
    __shared__ __align__(16) int s_off[WPB][CPT + TAIL];  // (cid<<9)+sco
    __shared__ int s_sid[WPB][CPT + TAIL];
    __shared__ float r_scr[3][WPB];

    const int tid  = threadIdx.x;
    const int lane = tid & 63;
    const int wid  = tid >> 6;
    const int colb = lane << 2;               // byte offset of lane's column

    float ht = 0.f, tt = 0.f, hh = 0.f;

    const int slice = blockIdx.x & 1;         // XCD-parity slice mapping
    const int sco   = slice << 8;             // slice*64 cols*4B
    const int chunk = (blockIdx.x >> 1) * WPB + wid;
    const int start = chunk * CPT;
    const int len   = min(CPT, total_chars - start);
    const int sl    = min(CPT + TAIL, total_chars - start);
    const char* cb  = (const char*)char_emb;
    const float* ee = ent + slice * HALF + lane;

    // ---- stage offsets + sids (wave-local region) ----
    for (int c = lane; c < sl; c += 64) {
        s_off[wid][c] = (char_ids[start + c] << 9) + sco;
        s_sid[wid][c] = seg_ids[start + c];
    }
    // ---- boundary masks, kept in SGPRs (ballot is wave-uniform) ----
    unsigned long long mk[4] = {0ull, 0ull, 0ull, 0ull};
    if (len == CPT) {
#pragma unroll
        for (int grp = 0; grp < 4; ++grp) {
            const int c = start + grp * 64 + lane;
            const int s1 = seg_ids[c];
            const int s0 = (c > 0) ? seg_ids[c - 1] : (s1 + 1); // char 0: boundary
            mk[grp] = __ballot(s1 != s0);
            // empty triples between s0 and s1: statistically never taken
            unsigned long long gapm = __ballot(s1 > s0 + 1);
            while (gapm) {
                const int l  = __ffsll((long long)gapm) - 1;
                const int g0 = __shfl(s0, l);
                const int g1 = __shfl(s1, l);
                for (int g = g0 + 1; g < g1; ++g) {
                    const float gv = ee[(size_t)head_ids[g] * DIM];
                    hh = fmaf(gv, gv, hh);
                }
                gapm &= gapm - 1;
            }
        }
    }
    __syncthreads();

    if (len == CPT) {
        // -------- fast path --------
        int cur = __builtin_amdgcn_readfirstlane(s_sid[wid][0]);
        float hv = ee[(size_t)head_ids[cur] * DIM];   // prefetched head row val
        float acc = 0.f;
        bool live = false;      // first flush dropped iff chunk starts mid-segment
        float vA[16], vB[16];

#define PF(BUF, B) { \
    _Pragma("unroll") \
    for (int q = 0; q < 4; ++q) { \
        const int4 o4 = *(const int4*)&s_off[wid][(B) * 16 + q * 4]; \
        BUF[q * 4 + 0] = *(const float*)(cb + (size_t)(unsigned)(o4.x + colb)); \
        BUF[q * 4 + 1] = *(const float*)(cb + (size_t)(unsigned)(o4.y + colb)); \
        BUF[q * 4 + 2] = *(const float*)(cb + (size_t)(unsigned)(o4.z + colb)); \
        BUF[q * 4 + 3] = *(const float*)(cb + (size_t)(unsigned)(o4.w + colb)); \
    } }

#define CS(BUF, B) { \
    _Pragma("unroll") \
    for (int j = 0; j < 16; ++j) { \
        if (mk[(B) >> 2] & (1ull << (((B) & 3) * 16 + j))) {   /* scalar bit test */ \
            if (live) { ht = fmaf(hv, acc, ht); tt = fmaf(acc, acc, tt); } \
            live = true; \
            acc = 0.f; \
            cur = __builtin_amdgcn_readfirstlane(s_sid[wid][(B) * 16 + j]); \
            hv = ee[(size_t)head_ids[cur] * DIM];    /* s_load id + prefetch row */ \
            hh = fmaf(hv, hv, hh);                   /* boundary event: ||h||^2 */ \
        } \
        acc += BUF[j]; \
    } }

        PF(vA, 0)
#pragma unroll
        for (int B = 0; B < 16; ++B) {
            if (B + 1 < 16) { if (B & 1) { PF(vA, B + 1) } else { PF(vB, B + 1) } }
            if (B & 1) { CS(vB, B) } else { CS(vA, B) }
        }

        if (live) {
            // tail: last owned segment may continue past chunk end
            int e = CPT;
            bool ended = false;
            while (e < sl) {
                const int idx = e + lane;
                const bool differ = (idx < sl) && (s_sid[wid][idx] != cur);
                const unsigned long long bm = __ballot(differ);
                const int run = bm ? (__ffsll((long long)bm) - 1)
                                   : min(64, sl - e);
                for (int j = 0; j < run; j += 4) {
                    const int mm2 = min(4, run - j);
                    float vv[4];
#pragma unroll
                    for (int k = 0; k < 4; ++k) {
                        if (k < mm2)
                            vv[k] = *(const float*)(cb +
                                (size_t)(unsigned)(s_off[wid][e + j + k] + colb));
                    }
                    for (int k = 0; k < mm2; ++k) acc += vv[k];
                }
                e += run;
                if (bm) { ended = true; break; }
            }
            if (!ended && start + sl < total_chars) {
                int gg = start + sl;                 // very rare long run
                while (gg < total_chars && seg_ids[gg] == cur) {
                    acc += *(const float*)(cb +
                        (size_t)(unsigned)((char_ids[gg] << 9) + sco + colb));
                    ++gg;
                }
            }
            // final flush
            ht = fmaf(hv, acc, ht);
            tt = fmaf(acc, acc, tt);
        }
    } else if (len > 0) {
        // -------- rare fallback (partial last chunk): scalar per char --------
        const float* cembF = char_emb + slice * HALF + lane;
        int p = 0;
        if (start > 0) {
            const int prev = seg_ids[start - 1];
            while (p < len && seg_ids[start + p] == prev) ++p;
        }
        if (p < len) {
            int cur2 = seg_ids[start + p];
            if (start > 0) {                     // gap before first owned segment
                for (int g = seg_ids[start - 1] + 1; g < cur2; ++g) {
                    const float gv = ee[(size_t)head_ids[g] * DIM];
                    hh = fmaf(gv, gv, hh);
                }
            }
            float acc = 0.f;
            float hv = ee[(size_t)head_ids[cur2] * DIM];
            hh = fmaf(hv, hv, hh);
            for (int c = p; c < len; ++c) {
                const int sid = seg_ids[start + c];
                if (sid != cur2) {
                    ht += hv * acc; tt += acc * acc;
                    for (int g = cur2 + 1; g < sid; ++g) {   // interior gaps
                        const float gv = ee[(size_t)head_ids[g] * DIM];
                        hh = fmaf(gv, gv, hh);
                    }
                    acc = 0.f; cur2 = sid;
                    hv = ee[(size_t)head_ids[cur2] * DIM];
                    hh = fmaf(hv, hv, hh);
                }
                acc += cembF[(size_t)char_ids[start + c] * DIM];
            }
            int gg = start + len;
            while (gg < total_chars && seg_ids[gg] == cur2) {
                acc += cembF[(size_t)char_ids[gg] * DIM];
                ++gg;
            }
            ht += hv * acc; tt += acc * acc;
        }
    }

    // -------- block reduce -> per-block partials (no atomics, no memset) ----
#pragma unroll
    for (int off = 32; off > 0; off >>= 1) {
        ht += __shfl_down(ht, off);
        tt += __shfl_down(tt, off);
        hh += __shfl_down(hh, off);
    }
    if (lane == 0) { r_scr[0][wid] = ht; r_scr[1][wid] = tt; r_scr[2][wid] = hh; }
    __syncthreads();
    if (tid == 0) {
        float a = 0.f, b = 0.f, c = 0.f;
#pragma unroll
        for (int w = 0; w < WPB; ++w) {
            a += r_scr[0][w]; b += r_scr[1][w]; c += r_scr[2][w];
        }
        pb[blockIdx.x * 3 + 0] = a;
        pb[blockIdx.x * 3 + 1] = b;
        pb[blockIdx.x * 3 + 2] = c;
    }
}

// final reduce: sums partials in double, adds hh for leading/trailing empty
// triples (rows with no chars before the first / after the last seg id),
// writes N - ht/sqrt(hh*tt)
__global__ __launch_bounds__(256) void reduce_kernel(
    const float* __restrict__ pb, int nb, float* __restrict__ out,
    int n_triples, const int* __restrict__ seg_ids,
    const int* __restrict__ head_ids, const float* __restrict__ ent,
    int total_chars)
{
    double ht = 0.0, tt = 0.0, hh = 0.0;
    for (int i = threadIdx.x; i < nb; i += 256) {
        ht += (double)pb[i * 3 + 0];
        tt += (double)pb[i * 3 + 1];
        hh += (double)pb[i * 3 + 2];
    }
    // leading/trailing empty triples (typically 0)
    int first = n_triples, last = n_triples - 1;
    if (total_chars > 0) { first = seg_ids[0]; last = seg_ids[total_chars - 1]; }
    const int lead  = first;
    const int trail = n_triples - 1 - last;
    const int tot   = lead + trail;
    const float4* e4 = (const float4*)ent;
    for (int w = threadIdx.x; w < tot * 32; w += 256) {
        const int rr = w >> 5;
        const int g  = (rr < lead) ? rr : (last + 1 + (rr - lead));
        const float4 v = e4[(size_t)head_ids[g] * 32 + (w & 31)];
        hh += (double)v.x * v.x + (double)v.y * v.y
            + (double)v.z * v.z + (double)v.w * v.w;
    }
#pragma unroll
    for (int off = 32; off > 0; off >>= 1) {
        ht += __shfl_down(ht, off);
        tt += __shfl_down(tt, off);
        hh += __shfl_down(hh, off);
    }
    __shared__ double sd[3][4];
    const int wid = threadIdx.x >> 6;
    if ((threadIdx.x & 63) == 0) { sd[0][wid] = ht; sd[1][wid] = tt; sd[2][wid] = hh; }
    __syncthreads();
    if (threadIdx.x == 0) {
        double a = 0.0, b = 0.0, c = 0.0;
        for (int w = 0; w < 4; ++w) { a += sd[0][w]; b += sd[1][w]; c += sd[2][w]; }
        out[0] = (float)((double)n_triples - a / sqrt(c * b));
    }
}

extern "C" void kernel_launch(void* const* d_in, const int* in_sizes, int n_in,
                              void* d_out, int out_size, void* d_ws, size_t ws_size,
                              hipStream_t stream)
{
    const float* char_emb = (const float*)d_in[0];
    const float* ent_emb  = (const float*)d_in[1];
    const int* head_ids   = (const int*)d_in[2];
    const int* char_ids   = (const int*)d_in[3];
    const int* seg_ids    = (const int*)d_in[4];
    const int n_triples   = in_sizes[2];
    const int total_chars = in_sizes[3];

    const int n_chunks = (total_chars + CPT - 1) / CPT;
    const int bps = (n_chunks + WPB - 1) / WPB;
    const int nsb = (2 * bps > 0) ? 2 * bps : 2;   // x2 slices

    float* pb = (float*)d_ws;                      // nsb*3 floats

    fused_kernel<<<nsb, 256, 0, stream>>>(char_emb, ent_emb, head_ids,
                                          char_ids, seg_ids, pb,
                                          total_chars);
    reduce_kernel<<<1, 256, 0, stream>>>(pb, nsb, (float*)d_out, n_triples,
                                         seg_ids, head_ids, ent_emb,
                                         total_chars);
}